// Round 3
// baseline (930.156 us; speedup 1.0000x reference)
//
#include <hip/hip_runtime.h>
#include <cstdint>
#include <cstddef>

#define DEV __device__ __forceinline__

typedef __attribute__((ext_vector_type(4))) float  f32x4;
typedef __attribute__((ext_vector_type(4))) float  float4v;
typedef __attribute__((ext_vector_type(8))) short  s16x8;
typedef __attribute__((ext_vector_type(4))) short  s16x4;

static constexpr int BB = 2, SS = 2048, HIDN = 1024, NHH = 16, FFN = 4096, DH = 64;
static constexpr int TWOK = 1024;                  // 2*K
static constexpr int HG = 4;                       // heads per attention group
static constexpr float ATT_SCALE = 0.07216878364870322f;  // 1/sqrt(3*DH)

DEV short f2bf(float f) {
  union { float f; uint32_t u; } v; v.f = f;
  uint32_t r = (v.u + 0x7fffu + ((v.u >> 16) & 1u)) >> 16;
  return (short)r;
}
DEV float bfu(unsigned short u) {
  union { uint32_t u; float f; } v; v.u = ((uint32_t)u) << 16; return v.f;
}
DEV int imin(int a, int b) { return a < b ? a : b; }
DEV int imax(int a, int b) { return a > b ? a : b; }

DEV void gl_lds16(const void* g, void* l) {
  __builtin_amdgcn_global_load_lds((const __attribute__((address_space(1))) void*)g,
                                   (__attribute__((address_space(3))) void*)l, 16, 0, 0);
}

#define MFMA16(a, b, c) __builtin_amdgcn_mfma_f32_16x16x32_bf16((a), (b), (c), 0, 0, 0)

// ---------------------------------------------------------------- transpose+cast
__global__ __launch_bounds__(256) void k_tcast(const float* __restrict__ in,
                                               short* __restrict__ out, int R, int C) {
  __shared__ float t[32][33];
  const int bx = blockIdx.x * 32;   // C
  const int by = blockIdx.y * 32;   // R
  const int tx = threadIdx.x & 31, ty = threadIdx.x >> 5;
#pragma unroll
  for (int r = ty; r < 32; r += 8) t[r][tx] = in[(size_t)(by + r) * C + bx + tx];
  __syncthreads();
#pragma unroll
  for (int c = ty; c < 32; c += 8) out[(size_t)(bx + c) * R + by + tx] = f2bf(t[tx][c]);
}

// ---------------------------------------------------------------- plain cast
__global__ __launch_bounds__(256) void k_cast(const float* __restrict__ in,
                                              short* __restrict__ out, int n4) {
  const int i = blockIdx.x * 256 + threadIdx.x;
  if (i < n4) {
    float4v v = ((const float4v*)in)[i];
    s16x4 o; o[0] = f2bf(v.x); o[1] = f2bf(v.y); o[2] = f2bf(v.z); o[3] = f2bf(v.w);
    ((s16x4*)out)[i] = o;
  }
}

// ---------------------------------------------------------------- layernorm
__global__ __launch_bounds__(256) void k_ln(const float* __restrict__ x,
                                            const float* __restrict__ gw,
                                            const float* __restrict__ bw,
                                            short* __restrict__ out) {
  const int row = blockIdx.x, t = threadIdx.x, lane = t & 63, wv = t >> 6;
  __shared__ float red[8];
  const float4v v = ((const float4v*)(x + (size_t)row * HIDN))[t];
  float s = v.x + v.y + v.z + v.w;
#pragma unroll
  for (int d = 1; d < 64; d <<= 1) s += __shfl_xor(s, d, 64);
  if (lane == 0) red[wv] = s;
  __syncthreads();
  const float mean = (red[0] + red[1] + red[2] + red[3]) * (1.f / 1024.f);
  const float dx = v.x - mean, dy = v.y - mean, dz = v.z - mean, dw = v.w - mean;
  float s2 = dx * dx + dy * dy + dz * dz + dw * dw;
#pragma unroll
  for (int d = 1; d < 64; d <<= 1) s2 += __shfl_xor(s2, d, 64);
  if (lane == 0) red[4 + wv] = s2;
  __syncthreads();
  const float var = (red[4] + red[5] + red[6] + red[7]) * (1.f / 1024.f);
  const float rs = rsqrtf(var + 1e-6f);
  const float4v g4 = ((const float4v*)gw)[t], b4 = ((const float4v*)bw)[t];
  s16x4 o;
  o[0] = f2bf(dx * rs * g4.x + b4.x);
  o[1] = f2bf(dy * rs * g4.y + b4.y);
  o[2] = f2bf(dz * rs * g4.z + b4.z);
  o[3] = f2bf(dw * rs * g4.w + b4.w);
  ((s16x4*)(out + (size_t)row * HIDN))[t] = o;
}

// ---------------------------------------------------------------- GEMM (m97 structure)
enum { OM_HEADS = 0, OM_VT = 1, OM_POS = 2, OM_GELU = 3, OM_RESID = 4 };

template <int OM>
__global__ __launch_bounds__(256) void k_gemm(const short* __restrict__ A,
                                              const short* __restrict__ Bt,
                                              const float* __restrict__ bias,
                                              const float* __restrict__ resid,
                                              void* __restrict__ out,
                                              int M, int N, int K) {
  __shared__ short As[128 * 32];
  __shared__ short Bs[128 * 32];
  const int tid = threadIdx.x, lane = tid & 63;
  const int wave = tid >> 6;
  const int m0 = blockIdx.y * 128, n0 = blockIdx.x * 128;
  const int wm = (wave >> 1) * 64, wn = (wave & 1) * 64;
  const int lr = lane & 15, lg = lane >> 4;

  f32x4 acc[4][4];
#pragma unroll
  for (int i = 0; i < 4; ++i)
#pragma unroll
    for (int j = 0; j < 4; ++j) acc[i][j] = (f32x4){0.f, 0.f, 0.f, 0.f};

  for (int k0 = 0; k0 < K; k0 += 32) {
#pragma unroll
    for (int c = tid; c < 512; c += 256) {
      const int row = c >> 2, col = (c & 3) * 8;
      gl_lds16(A + (size_t)(m0 + row) * K + k0 + col, (char*)As + c * 16);
      gl_lds16(Bt + (size_t)(n0 + row) * K + k0 + col, (char*)Bs + c * 16);
    }
    __syncthreads();
    s16x8 af[4], bf[4];
#pragma unroll
    for (int fi = 0; fi < 4; ++fi) af[fi] = *(const s16x8*)&As[(wm + fi * 16 + lr) * 32 + lg * 8];
#pragma unroll
    for (int fj = 0; fj < 4; ++fj) bf[fj] = *(const s16x8*)&Bs[(wn + fj * 16 + lr) * 32 + lg * 8];
#pragma unroll
    for (int fi = 0; fi < 4; ++fi)
#pragma unroll
      for (int fj = 0; fj < 4; ++fj) acc[fi][fj] = MFMA16(af[fi], bf[fj], acc[fi][fj]);
    __syncthreads();
  }

#pragma unroll
  for (int fi = 0; fi < 4; ++fi)
#pragma unroll
    for (int fj = 0; fj < 4; ++fj) {
      const int n = n0 + wn + fj * 16 + lr;
      const float bv = bias ? bias[n] : 0.f;
#pragma unroll
      for (int r = 0; r < 4; ++r) {
        const int m = m0 + wm + fi * 16 + lg * 4 + r;
        float v = acc[fi][fj][r] + bv;
        if constexpr (OM == OM_HEADS) {
          const int b = m >> 11, s = m & (SS - 1);
          const int hh = n >> 6, dd = n & 63;
          ((short*)out)[(((size_t)b * NHH + hh) * SS + s) * DH + dd] = f2bf(v);
        } else if constexpr (OM == OM_VT) {
          const int b = m >> 11, s = m & (SS - 1);
          const int hh = n >> 6, dd = n & 63;
          ((short*)out)[(((size_t)b * NHH + hh) * DH + dd) * SS + s] = f2bf(v);
        } else if constexpr (OM == OM_POS) {
          const int hh = n >> 6, dd = n & 63;
          ((short*)out)[((size_t)hh * TWOK + m) * DH + dd] = f2bf(v);
        } else if constexpr (OM == OM_GELU) {
          const float th = tanhf(0.7978845608028654f * (v + 0.044715f * v * v * v));
          ((short*)out)[(size_t)m * N + n] = f2bf(0.5f * v * (1.f + th));
        } else {  // OM_RESID, fp32 out
          ((float*)out)[(size_t)m * N + n] = v + resid[(size_t)m * N + n];
        }
      }
    }
}

// ---------------------------------------------------------------- batched pos-attention GEMM
// Group version: heads [h0, h0+HG). out[b*HG+hl][m][r] = A[b,h0+hl][m][:64] . P[h0+hl][r][:64]
__global__ __launch_bounds__(256) void k_posgemm(const short* __restrict__ A,
                                                 const short* __restrict__ P,
                                                 short* __restrict__ out, int h0) {
  __shared__ short As[128 * 64];
  __shared__ short Bs[128 * 64];
  const int tid = threadIdx.x, lane = tid & 63, wave = tid >> 6;
  const int z = blockIdx.z;
  const int b = z >> 2, hl = z & 3;
  const int h = h0 + hl;
  const int m0 = blockIdx.y * 128, n0 = blockIdx.x * 128;
  const int wm = (wave >> 1) * 64, wn = (wave & 1) * 64;
  const int lr = lane & 15, lg = lane >> 4;
  const short* Ab = A + ((size_t)b * NHH + h) * SS * DH;
  const short* Pb = P + (size_t)h * TWOK * DH;

#pragma unroll
  for (int c = tid; c < 1024; c += 256) {
    const int row = c >> 3, col = (c & 7) * 8;
    gl_lds16(Ab + (size_t)(m0 + row) * DH + col, (char*)As + c * 16);
    gl_lds16(Pb + (size_t)(n0 + row) * DH + col, (char*)Bs + c * 16);
  }
  __syncthreads();

  f32x4 acc[4][4];
#pragma unroll
  for (int i = 0; i < 4; ++i)
#pragma unroll
    for (int j = 0; j < 4; ++j) acc[i][j] = (f32x4){0.f, 0.f, 0.f, 0.f};

#pragma unroll
  for (int ks = 0; ks < 2; ++ks) {
    s16x8 af[4], bf[4];
#pragma unroll
    for (int fi = 0; fi < 4; ++fi) af[fi] = *(const s16x8*)&As[(wm + fi * 16 + lr) * 64 + ks * 32 + lg * 8];
#pragma unroll
    for (int fj = 0; fj < 4; ++fj) bf[fj] = *(const s16x8*)&Bs[(wn + fj * 16 + lr) * 64 + ks * 32 + lg * 8];
#pragma unroll
    for (int fi = 0; fi < 4; ++fi)
#pragma unroll
      for (int fj = 0; fj < 4; ++fj) acc[fi][fj] = MFMA16(af[fi], bf[fj], acc[fi][fj]);
  }

  short* ob = out + ((size_t)b * HG + hl) * SS * TWOK;
#pragma unroll
  for (int fi = 0; fi < 4; ++fi)
#pragma unroll
    for (int fj = 0; fj < 4; ++fj)
#pragma unroll
      for (int r = 0; r < 4; ++r)
        ob[(size_t)(m0 + wm + fi * 16 + lg * 4 + r) * TWOK + n0 + wn + fj * 16 + lr] =
            f2bf(acc[fi][fj][r]);
}

// ---------------------------------------------------------------- flash disentangled attention
// Heads [h0, h0+HG). c2p/p2c indexed by local bh = b*HG+hl. Waves fully independent
// (Ps bands are per-wave private -> no barriers).
__global__ __launch_bounds__(256) void k_attn(const short* __restrict__ qh,
                                              const short* __restrict__ kh,
                                              const short* __restrict__ vT,
                                              const short* __restrict__ c2p,
                                              const short* __restrict__ p2c,
                                              const int* __restrict__ mask,
                                              short* __restrict__ ao, int h0) {
  __shared__ short Ps[64 * 72];   // per-wave 16-row bands, stride 72 shorts

  const int tid = threadIdx.x, lane = tid & 63, wv = tid >> 6;
  const int lr = lane & 15, lg = lane >> 4;
  const int band = wv * 16;

  const int bid = blockIdx.x;           // 256 = 2b * 4hl * 32 itiles
  const int itile = bid & 31;
  const int hl = (bid >> 5) & 3;
  const int b = bid >> 7;
  const int h = h0 + hl;
  const int i0 = itile * 64;
  const size_t bhoff = ((size_t)b * NHH + h) * SS * DH;
  const size_t bhl = (size_t)b * HG + hl;

  // Q fragment in registers (A-frag rows i0+band+lr)
  const short* qrow = qh + bhoff + (size_t)(i0 + band + lr) * DH + lg * 8;
  const s16x8 qa0 = *(const s16x8*)qrow;
  const s16x8 qa1 = *(const s16x8*)(qrow + 32);

  // c2p row base pointers for the 4 output rows this lane owns
  const unsigned short* c2prow[4];
#pragma unroll
  for (int r = 0; r < 4; ++r)
    c2prow[r] = (const unsigned short*)(c2p + (bhl * SS + (size_t)(i0 + band + lg * 4 + r)) * TWOK);
  const unsigned short* p2cb = (const unsigned short*)(p2c + bhl * SS * TWOK);

  const int dbase = i0 + band + lg * 4 - lr;   // delta = dbase + r - 16*fj - 64*jt

  f32x4 oacc[4];
  float mprev[4], lsum[4];
#pragma unroll
  for (int r = 0; r < 4; ++r) {
    mprev[r] = -1e30f; lsum[r] = 0.f; oacc[r] = (f32x4){0.f, 0.f, 0.f, 0.f};
  }

  for (int jt = 0; jt < SS / 64; ++jt) {
    const int j0 = jt * 64;

    // ---- c2c scores via MFMA (K frags from L1/L2)
    f32x4 sacc[4];
#pragma unroll
    for (int fj = 0; fj < 4; ++fj) {
      const short* krow = kh + bhoff + (size_t)(j0 + fj * 16 + lr) * DH + lg * 8;
      const s16x8 k0 = *(const s16x8*)krow;
      const s16x8 k1 = *(const s16x8*)(krow + 32);
      f32x4 a = (f32x4){0.f, 0.f, 0.f, 0.f};
      a = MFMA16(qa0, k0, a);
      a = MFMA16(qa1, k1, a);
      sacc[fj] = a;
    }

    // ---- gather c2p/p2c, mask, scale
    float pv[4][4];
#pragma unroll
    for (int fj = 0; fj < 4; ++fj) {
      const int jl = fj * 16 + lr;
      const bool ok = mask[(size_t)b * SS + j0 + jl] != 0;
      const unsigned short* prow = p2cb + (size_t)(j0 + jl) * TWOK;
      const int dl0 = dbase - fj * 16 - j0;
#pragma unroll
      for (int r = 0; r < 4; ++r) {
        const int dl = dl0 + r;
        const int cc = imin(imax(dl + 512, 0), 1023);   // rel(i,j)
        const int cp = imin(imax(512 - dl, 0), 1023);   // rel(j,i)
        const float s = (sacc[fj][r] + bfu(c2prow[r][cc]) + bfu(prow[cp])) * ATT_SCALE;
        pv[fj][r] = ok ? s : -1e9f;
      }
    }

    // ---- online softmax (rows spread over 16 lanes within lg-group)
#pragma unroll
    for (int r = 0; r < 4; ++r) {
      float m = fmaxf(fmaxf(pv[0][r], pv[1][r]), fmaxf(pv[2][r], pv[3][r]));
#pragma unroll
      for (int dd = 1; dd < 16; dd <<= 1) m = fmaxf(m, __shfl_xor(m, dd, 64));
      const float mnew = fmaxf(mprev[r], m);
      const float corr = __expf(mprev[r] - mnew);
      float rs = 0.f;
#pragma unroll
      for (int fj = 0; fj < 4; ++fj) { pv[fj][r] = __expf(pv[fj][r] - mnew); rs += pv[fj][r]; }
#pragma unroll
      for (int dd = 1; dd < 16; dd <<= 1) rs += __shfl_xor(rs, dd, 64);
      lsum[r] = lsum[r] * corr + rs;
      mprev[r] = mnew;
#pragma unroll
      for (int fd = 0; fd < 4; ++fd) oacc[fd][r] *= corr;
    }

    // ---- P -> LDS transpose (per-wave private band; no barrier needed)
#pragma unroll
    for (int fj = 0; fj < 4; ++fj)
#pragma unroll
      for (int r = 0; r < 4; ++r)
        Ps[(band + lg * 4 + r) * 72 + fj * 16 + lr] = f2bf(pv[fj][r]);

    // ---- PV (V frags from L1/L2)
    const s16x8 pa0 = *(const s16x8*)&Ps[(band + lr) * 72 + lg * 8];
    const s16x8 pa1 = *(const s16x8*)&Ps[(band + lr) * 72 + 32 + lg * 8];
#pragma unroll
    for (int fd = 0; fd < 4; ++fd) {
      const short* vrow = vT + bhoff + (size_t)(fd * 16 + lr) * SS + j0 + lg * 8;
      const s16x8 v0 = *(const s16x8*)vrow;
      const s16x8 v1 = *(const s16x8*)(vrow + 32);
      oacc[fd] = MFMA16(pa0, v0, oacc[fd]);
      oacc[fd] = MFMA16(pa1, v1, oacc[fd]);
    }
  }

  // epilogue
#pragma unroll
  for (int fd = 0; fd < 4; ++fd) {
    const int d = h * DH + fd * 16 + lr;
#pragma unroll
    for (int r = 0; r < 4; ++r) {
      const int ig = i0 + band + lg * 4 + r;
      ao[((size_t)b * SS + ig) * HIDN + d] = f2bf(oacc[fd][r] / lsum[r]);
    }
  }
}

// ---------------------------------------------------------------- launch
extern "C" void kernel_launch(void* const* d_in, const int* in_sizes, int n_in,
                              void* d_out, int out_size, void* d_ws, size_t ws_size,
                              hipStream_t stream) {
  const float* x   = (const float*)d_in[0];
  const int* mask  = (const int*)d_in[1];
  const float* Wq  = (const float*)d_in[2];  const float* bq  = (const float*)d_in[3];
  const float* Wk  = (const float*)d_in[4];  const float* bk  = (const float*)d_in[5];
  const float* Wv  = (const float*)d_in[6];  const float* bv  = (const float*)d_in[7];
  const float* Wo  = (const float*)d_in[8];  const float* bo  = (const float*)d_in[9];
  const float* rel = (const float*)d_in[10];
  const float* Wpk = (const float*)d_in[11]; const float* bpk = (const float*)d_in[12];
  const float* Wpq = (const float*)d_in[13]; const float* bpq = (const float*)d_in[14];
  const float* g1  = (const float*)d_in[15]; const float* be1 = (const float*)d_in[16];
  const float* g2  = (const float*)d_in[17]; const float* be2 = (const float*)d_in[18];
  const float* W1  = (const float*)d_in[19]; const float* bf1 = (const float*)d_in[20];
  const float* W2  = (const float*)d_in[21]; const float* bf2 = (const float*)d_in[22];
  float* out = (float*)d_out;

  // ---- explicit liveness-based layout, total 100 MB (< 114 MB proven in R1) ----
  char* ws = (char*)d_ws;
  const size_t MB = (size_t)1 << 20;
  // persistent
  short* aoB   = (short*)(ws + 0 * MB);    // 8 MB, attn out, live until O-proj
  short* qhB   = (short*)(ws + 8 * MB);    // 8 MB
  short* khB   = (short*)(ws + 16 * MB);   // 8 MB
  short* vTB   = (short*)(ws + 24 * MB);   // 8 MB
  short* poskB = (short*)(ws + 32 * MB);   // 2 MB
  short* posqB = (short*)(ws + 34 * MB);   // 2 MB
  // transient region T = [36 MB, 100 MB)
  // stage 1-3 (dead before group loop):
  short* xn    = (short*)(ws + 36 * MB);   // 8 MB
  short* WqT   = (short*)(ws + 44 * MB);   // 2 MB
  short* WkT   = (short*)(ws + 46 * MB);   // 2 MB
  short* WvT   = (short*)(ws + 48 * MB);   // 2 MB
  short* WpkT  = (short*)(ws + 50 * MB);   // 2 MB
  short* WpqT  = (short*)(ws + 52 * MB);   // 2 MB
  short* relbf = (short*)(ws + 54 * MB);   // 2 MB
  // stage 4 (group loop):
  short* c2pG  = (short*)(ws + 36 * MB);   // 32 MB  [B, HG, S, 2K] bf16
  short* p2cG  = (short*)(ws + 68 * MB);   // 32 MB
  // stage 5 (after attention; c2p/p2c dead):
  short* WoT   = (short*)(ws + 68 * MB);   // 2 MB
  short* hnB   = (short*)(ws + 70 * MB);   // 8 MB
  short* W1T   = (short*)(ws + 78 * MB);   // 8 MB
  short* W2T   = (short*)(ws + 86 * MB);   // 8 MB
  short* midB  = (short*)(ws + 36 * MB);   // 32 MB
  (void)ws_size; (void)in_sizes; (void)n_in; (void)out_size;

  const int M = BB * SS;  // 4096

  // ---- stage 1: prep for sublayer 1
  k_tcast<<<dim3(32, 32), 256, 0, stream>>>(Wq, WqT, 1024, 1024);
  k_tcast<<<dim3(32, 32), 256, 0, stream>>>(Wk, WkT, 1024, 1024);
  k_tcast<<<dim3(32, 32), 256, 0, stream>>>(Wv, WvT, 1024, 1024);
  k_tcast<<<dim3(32, 32), 256, 0, stream>>>(Wpk, WpkT, 1024, 1024);
  k_tcast<<<dim3(32, 32), 256, 0, stream>>>(Wpq, WpqT, 1024, 1024);
  k_cast<<<1024, 256, 0, stream>>>(rel, relbf, 1024 * 1024 / 4);
  k_ln<<<M, 256, 0, stream>>>(x, g1, be1, xn);

  // ---- stage 2: projections
  k_gemm<OM_HEADS><<<dim3(8, 32), 256, 0, stream>>>(xn, WqT, bq, nullptr, qhB, M, 1024, 1024);
  k_gemm<OM_HEADS><<<dim3(8, 32), 256, 0, stream>>>(xn, WkT, bk, nullptr, khB, M, 1024, 1024);
  k_gemm<OM_VT><<<dim3(8, 32), 256, 0, stream>>>(xn, WvT, bv, nullptr, vTB, M, 1024, 1024);
  k_gemm<OM_POS><<<dim3(8, 8), 256, 0, stream>>>(relbf, WpkT, bpk, nullptr, poskB, 1024, 1024, 1024);
  k_gemm<OM_POS><<<dim3(8, 8), 256, 0, stream>>>(relbf, WpqT, bpq, nullptr, posqB, 1024, 1024, 1024);

  // ---- stage 4: attention in 4 head-groups (c2p/p2c reused per group)
  for (int g = 0; g < NHH / HG; ++g) {
    const int h0 = g * HG;
    k_posgemm<<<dim3(8, 16, BB * HG), 256, 0, stream>>>(qhB, poskB, c2pG, h0);
    k_posgemm<<<dim3(8, 16, BB * HG), 256, 0, stream>>>(khB, posqB, p2cG, h0);
    k_attn<<<BB * HG * 32, 256, 0, stream>>>(qhB, khB, vTB, c2pG, p2cG, mask, aoB, h0);
  }

  // ---- stage 5: O-proj + sublayer 2 (scratch reuses dead c2p/p2c space)
  k_tcast<<<dim3(32, 32), 256, 0, stream>>>(Wo, WoT, 1024, 1024);
  k_gemm<OM_RESID><<<dim3(8, 32), 256, 0, stream>>>(aoB, WoT, bo, x, out, M, 1024, 1024);
  k_ln<<<M, 256, 0, stream>>>(out, g2, be2, hnB);
  k_tcast<<<dim3(128, 32), 256, 0, stream>>>(W1, W1T, 1024, 4096);
  k_tcast<<<dim3(32, 128), 256, 0, stream>>>(W2, W2T, 4096, 1024);
  k_gemm<OM_GELU><<<dim3(32, 32), 256, 0, stream>>>(hnB, W1T, bf1, nullptr, midB, M, 4096, 1024);
  k_gemm<OM_RESID><<<dim3(8, 32), 256, 0, stream>>>(midB, W2T, bf2, out, out, M, 1024, 4096);
}

// Round 4
// 780.474 us; speedup vs baseline: 1.1918x; 1.1918x over previous
//
#include <hip/hip_runtime.h>
#include <cstdint>
#include <cstddef>

#define DEV __device__ __forceinline__

typedef __attribute__((ext_vector_type(4))) float  f32x4;
typedef __attribute__((ext_vector_type(4))) float  float4v;
typedef __attribute__((ext_vector_type(8))) short  s16x8;
typedef __attribute__((ext_vector_type(4))) short  s16x4;

static constexpr int BB = 2, SS = 2048, HIDN = 1024, NHH = 16, FFN = 4096, DH = 64;
static constexpr int TWOK = 1024;                  // 2*K
static constexpr int HG = 4;                       // heads per attention group
static constexpr float ATT_SCALE = 0.07216878364870322f;  // 1/sqrt(3*DH)

DEV short f2bf(float f) {
  union { float f; uint32_t u; } v; v.f = f;
  uint32_t r = (v.u + 0x7fffu + ((v.u >> 16) & 1u)) >> 16;
  return (short)r;
}
DEV float bfu(unsigned short u) {
  union { uint32_t u; float f; } v; v.u = ((uint32_t)u) << 16; return v.f;
}
DEV int imin(int a, int b) { return a < b ? a : b; }
DEV int imax(int a, int b) { return a > b ? a : b; }

DEV void gl_lds16(const void* g, void* l) {
  __builtin_amdgcn_global_load_lds((const __attribute__((address_space(1))) void*)g,
                                   (__attribute__((address_space(3))) void*)l, 16, 0, 0);
}

#define MFMA16(a, b, c) __builtin_amdgcn_mfma_f32_16x16x32_bf16((a), (b), (c), 0, 0, 0)

// ---------------------------------------------------------------- transpose+cast
__global__ __launch_bounds__(256) void k_tcast(const float* __restrict__ in,
                                               short* __restrict__ out, int R, int C) {
  __shared__ float t[32][33];
  const int bx = blockIdx.x * 32;   // C
  const int by = blockIdx.y * 32;   // R
  const int tx = threadIdx.x & 31, ty = threadIdx.x >> 5;
#pragma unroll
  for (int r = ty; r < 32; r += 8) t[r][tx] = in[(size_t)(by + r) * C + bx + tx];
  __syncthreads();
#pragma unroll
  for (int c = ty; c < 32; c += 8) out[(size_t)(bx + c) * R + by + tx] = f2bf(t[tx][c]);
}

// ---------------------------------------------------------------- plain cast
__global__ __launch_bounds__(256) void k_cast(const float* __restrict__ in,
                                              short* __restrict__ out, int n4) {
  const int i = blockIdx.x * 256 + threadIdx.x;
  if (i < n4) {
    float4v v = ((const float4v*)in)[i];
    s16x4 o; o[0] = f2bf(v.x); o[1] = f2bf(v.y); o[2] = f2bf(v.z); o[3] = f2bf(v.w);
    ((s16x4*)out)[i] = o;
  }
}

// ---------------------------------------------------------------- layernorm
__global__ __launch_bounds__(256) void k_ln(const float* __restrict__ x,
                                            const float* __restrict__ gw,
                                            const float* __restrict__ bw,
                                            short* __restrict__ out) {
  const int row = blockIdx.x, t = threadIdx.x, lane = t & 63, wv = t >> 6;
  __shared__ float red[8];
  const float4v v = ((const float4v*)(x + (size_t)row * HIDN))[t];
  float s = v.x + v.y + v.z + v.w;
#pragma unroll
  for (int d = 1; d < 64; d <<= 1) s += __shfl_xor(s, d, 64);
  if (lane == 0) red[wv] = s;
  __syncthreads();
  const float mean = (red[0] + red[1] + red[2] + red[3]) * (1.f / 1024.f);
  const float dx = v.x - mean, dy = v.y - mean, dz = v.z - mean, dw = v.w - mean;
  float s2 = dx * dx + dy * dy + dz * dz + dw * dw;
#pragma unroll
  for (int d = 1; d < 64; d <<= 1) s2 += __shfl_xor(s2, d, 64);
  if (lane == 0) red[4 + wv] = s2;
  __syncthreads();
  const float var = (red[4] + red[5] + red[6] + red[7]) * (1.f / 1024.f);
  const float rs = rsqrtf(var + 1e-6f);
  const float4v g4 = ((const float4v*)gw)[t], b4 = ((const float4v*)bw)[t];
  s16x4 o;
  o[0] = f2bf(dx * rs * g4.x + b4.x);
  o[1] = f2bf(dy * rs * g4.y + b4.y);
  o[2] = f2bf(dz * rs * g4.z + b4.z);
  o[3] = f2bf(dw * rs * g4.w + b4.w);
  ((s16x4*)(out + (size_t)row * HIDN))[t] = o;
}

// ---------------------------------------------------------------- GEMM (m97 structure)
enum { OM_HEADS = 0, OM_VT = 1, OM_POS = 2, OM_GELU = 3, OM_RESID = 4 };

template <int OM>
__global__ __launch_bounds__(256) void k_gemm(const short* __restrict__ A,
                                              const short* __restrict__ Bt,
                                              const float* __restrict__ bias,
                                              const float* __restrict__ resid,
                                              void* __restrict__ out,
                                              int M, int N, int K) {
  __shared__ short As[128 * 32];
  __shared__ short Bs[128 * 32];
  const int tid = threadIdx.x, lane = tid & 63;
  const int wave = tid >> 6;
  const int m0 = blockIdx.y * 128, n0 = blockIdx.x * 128;
  const int wm = (wave >> 1) * 64, wn = (wave & 1) * 64;
  const int lr = lane & 15, lg = lane >> 4;

  f32x4 acc[4][4];
#pragma unroll
  for (int i = 0; i < 4; ++i)
#pragma unroll
    for (int j = 0; j < 4; ++j) acc[i][j] = (f32x4){0.f, 0.f, 0.f, 0.f};

  for (int k0 = 0; k0 < K; k0 += 32) {
#pragma unroll
    for (int c = tid; c < 512; c += 256) {
      const int row = c >> 2, col = (c & 3) * 8;
      gl_lds16(A + (size_t)(m0 + row) * K + k0 + col, (char*)As + c * 16);
      gl_lds16(Bt + (size_t)(n0 + row) * K + k0 + col, (char*)Bs + c * 16);
    }
    __syncthreads();
    s16x8 af[4], bf[4];
#pragma unroll
    for (int fi = 0; fi < 4; ++fi) af[fi] = *(const s16x8*)&As[(wm + fi * 16 + lr) * 32 + lg * 8];
#pragma unroll
    for (int fj = 0; fj < 4; ++fj) bf[fj] = *(const s16x8*)&Bs[(wn + fj * 16 + lr) * 32 + lg * 8];
#pragma unroll
    for (int fi = 0; fi < 4; ++fi)
#pragma unroll
      for (int fj = 0; fj < 4; ++fj) acc[fi][fj] = MFMA16(af[fi], bf[fj], acc[fi][fj]);
    __syncthreads();
  }

#pragma unroll
  for (int fi = 0; fi < 4; ++fi)
#pragma unroll
    for (int fj = 0; fj < 4; ++fj) {
      const int n = n0 + wn + fj * 16 + lr;
      const float bv = bias ? bias[n] : 0.f;
#pragma unroll
      for (int r = 0; r < 4; ++r) {
        const int m = m0 + wm + fi * 16 + lg * 4 + r;
        float v = acc[fi][fj][r] + bv;
        if constexpr (OM == OM_HEADS) {
          const int b = m >> 11, s = m & (SS - 1);
          const int hh = n >> 6, dd = n & 63;
          ((short*)out)[(((size_t)b * NHH + hh) * SS + s) * DH + dd] = f2bf(v);
        } else if constexpr (OM == OM_VT) {
          const int b = m >> 11, s = m & (SS - 1);
          const int hh = n >> 6, dd = n & 63;
          ((short*)out)[(((size_t)b * NHH + hh) * DH + dd) * SS + s] = f2bf(v);
        } else if constexpr (OM == OM_POS) {
          const int hh = n >> 6, dd = n & 63;
          ((short*)out)[((size_t)hh * TWOK + m) * DH + dd] = f2bf(v);
        } else if constexpr (OM == OM_GELU) {
          const float th = tanhf(0.7978845608028654f * (v + 0.044715f * v * v * v));
          ((short*)out)[(size_t)m * N + n] = f2bf(0.5f * v * (1.f + th));
        } else {  // OM_RESID, fp32 out
          ((float*)out)[(size_t)m * N + n] = v + resid[(size_t)m * N + n];
        }
      }
    }
}

// ---------------------------------------------------------------- merged pos-attention GEMM
// z = [isP2c:1][b:1][hl:2]. c2p[b*HG+hl][m][r] = q . posk ; p2c[...] = k . posq.
// p2c epilogue also extracts dense edge columns r=0 and r=1023 -> p2cE[bhl][2][S].
__global__ __launch_bounds__(256) void k_posgemm(const short* __restrict__ qh,
                                                 const short* __restrict__ kh,
                                                 const short* __restrict__ posk,
                                                 const short* __restrict__ posq,
                                                 short* __restrict__ c2pO,
                                                 short* __restrict__ p2cO,
                                                 short* __restrict__ p2cE, int h0) {
  __shared__ short As[128 * 64];
  __shared__ short Bs[128 * 64];
  const int tid = threadIdx.x, lane = tid & 63, wave = tid >> 6;
  const int z = blockIdx.z;
  const int hl = z & 3, b = (z >> 2) & 1, isP = z >> 3;
  const int h = h0 + hl;
  const int bhl = b * HG + hl;
  const int m0 = blockIdx.y * 128, n0 = blockIdx.x * 128;
  const int wm = (wave >> 1) * 64, wn = (wave & 1) * 64;
  const int lr = lane & 15, lg = lane >> 4;
  const short* Ab = (isP ? kh : qh) + ((size_t)b * NHH + h) * SS * DH;
  const short* Pb = (isP ? posq : posk) + (size_t)h * TWOK * DH;
  short* ob = (isP ? p2cO : c2pO) + (size_t)bhl * SS * TWOK;

#pragma unroll
  for (int c = tid; c < 1024; c += 256) {
    const int row = c >> 3, col = (c & 7) * 8;
    gl_lds16(Ab + (size_t)(m0 + row) * DH + col, (char*)As + c * 16);
    gl_lds16(Pb + (size_t)(n0 + row) * DH + col, (char*)Bs + c * 16);
  }
  __syncthreads();

  f32x4 acc[4][4];
#pragma unroll
  for (int i = 0; i < 4; ++i)
#pragma unroll
    for (int j = 0; j < 4; ++j) acc[i][j] = (f32x4){0.f, 0.f, 0.f, 0.f};

#pragma unroll
  for (int ks = 0; ks < 2; ++ks) {
    s16x8 af[4], bf[4];
#pragma unroll
    for (int fi = 0; fi < 4; ++fi) af[fi] = *(const s16x8*)&As[(wm + fi * 16 + lr) * 64 + ks * 32 + lg * 8];
#pragma unroll
    for (int fj = 0; fj < 4; ++fj) bf[fj] = *(const s16x8*)&Bs[(wn + fj * 16 + lr) * 64 + ks * 32 + lg * 8];
#pragma unroll
    for (int fi = 0; fi < 4; ++fi)
#pragma unroll
      for (int fj = 0; fj < 4; ++fj) acc[fi][fj] = MFMA16(af[fi], bf[fj], acc[fi][fj]);
  }

#pragma unroll
  for (int fi = 0; fi < 4; ++fi)
#pragma unroll
    for (int fj = 0; fj < 4; ++fj) {
      const int n = n0 + wn + fj * 16 + lr;
#pragma unroll
      for (int r = 0; r < 4; ++r) {
        const int m = m0 + wm + fi * 16 + lg * 4 + r;
        const short val = f2bf(acc[fi][fj][r]);
        ob[(size_t)m * TWOK + n] = val;
        if (isP) {
          if (n == 0)        p2cE[((size_t)bhl * 2 + 0) * SS + m] = val;
          if (n == TWOK - 1) p2cE[((size_t)bhl * 2 + 1) * SS + m] = val;
        }
      }
    }
}

// ---------------------------------------------------------------- flash disentangled attention
// Block: 16 i-rows, 4 waves = 4 j-quarters (split-KV). Saturated far tiles skip gathers.
__global__ __launch_bounds__(256) void k_attn(const short* __restrict__ qh,
                                              const short* __restrict__ kh,
                                              const short* __restrict__ vT,
                                              const short* __restrict__ c2p,
                                              const short* __restrict__ p2c,
                                              const short* __restrict__ p2cE,
                                              const int* __restrict__ mask,
                                              short* __restrict__ ao, int h0) {
  __shared__ float Om[4][16][68];
  __shared__ float Mm[4][16];
  __shared__ float Lm[4][16];
  __shared__ short Ps[4][16][72];

  const int tid = threadIdx.x, lane = tid & 63, wv = tid >> 6;
  const int lr = lane & 15, lg = lane >> 4;

  const int bid = blockIdx.x;            // 1024 = b:1 | hl:2 | itile:7
  const int itile = bid & 127;
  const int hl = (bid >> 7) & 3;
  const int b = bid >> 9;
  const int h = h0 + hl;
  const int i0 = itile * 16;
  const size_t bhoff = ((size_t)b * NHH + h) * SS * DH;
  const size_t bhl = (size_t)b * HG + hl;
  const int jq0 = wv * (SS / 4);

  // Q A-frag (rows i0..i0+15)
  const short* qrow = qh + bhoff + (size_t)(i0 + lr) * DH + lg * 8;
  const s16x8 qa0 = *(const s16x8*)qrow;
  const s16x8 qa1 = *(const s16x8*)(qrow + 32);

  // c2p rows for this lane's 4 output rows + saturation constants
  const unsigned short* c2prow[4];
  float cLoV[4], cHiV[4];
#pragma unroll
  for (int r = 0; r < 4; ++r) {
    c2prow[r] = (const unsigned short*)(c2p + (bhl * SS + (size_t)(i0 + lg * 4 + r)) * TWOK);
    cLoV[r] = bfu(c2prow[r][0]);
    cHiV[r] = bfu(c2prow[r][TWOK - 1]);
  }
  const unsigned short* p2cb = (const unsigned short*)(p2c + bhl * SS * TWOK);
  const unsigned short* pE0 = (const unsigned short*)(p2cE + (bhl * 2 + 0) * SS);
  const unsigned short* pE1 = (const unsigned short*)(p2cE + (bhl * 2 + 1) * SS);

  const int dbase = i0 + lg * 4 - lr;    // dl = dbase + r - 16*fj - j0

  f32x4 oacc[4];
  float mprev[4], lsum[4];
#pragma unroll
  for (int r = 0; r < 4; ++r) {
    mprev[r] = -1e30f; lsum[r] = 0.f; oacc[r] = (f32x4){0.f, 0.f, 0.f, 0.f};
  }

  for (int jt = 0; jt < SS / 4 / 64; ++jt) {   // 8 tiles per wave
    const int j0 = jq0 + jt * 64;
    const int d0 = i0 - j0;

    // ---- c2c scores via MFMA (K frags from L1/L2)
    f32x4 sacc[4];
#pragma unroll
    for (int fj = 0; fj < 4; ++fj) {
      const short* krow = kh + bhoff + (size_t)(j0 + fj * 16 + lr) * DH + lg * 8;
      const s16x8 k0 = *(const s16x8*)krow;
      const s16x8 k1 = *(const s16x8*)(krow + 32);
      f32x4 a = (f32x4){0.f, 0.f, 0.f, 0.f};
      a = MFMA16(qa0, k0, a);
      a = MFMA16(qa1, k1, a);
      sacc[fj] = a;
    }

    // ---- position terms
    float pvv[4][4];
    if (d0 >= 576) {          // fully hi-saturated: cc==1023, cp==0
#pragma unroll
      for (int fj = 0; fj < 4; ++fj) {
        const int jl = fj * 16 + lr;
        const bool ok = mask[(size_t)b * SS + j0 + jl] != 0;
        const float pe = bfu(pE0[j0 + jl]);
#pragma unroll
        for (int r = 0; r < 4; ++r) {
          const float s = (sacc[fj][r] + cHiV[r] + pe) * ATT_SCALE;
          pvv[fj][r] = ok ? s : -1e9f;
        }
      }
    } else if (d0 <= -528) {  // fully lo-saturated: cc==0, cp==1023
#pragma unroll
      for (int fj = 0; fj < 4; ++fj) {
        const int jl = fj * 16 + lr;
        const bool ok = mask[(size_t)b * SS + j0 + jl] != 0;
        const float pe = bfu(pE1[j0 + jl]);
#pragma unroll
        for (int r = 0; r < 4; ++r) {
          const float s = (sacc[fj][r] + cLoV[r] + pe) * ATT_SCALE;
          pvv[fj][r] = ok ? s : -1e9f;
        }
      }
    } else {                  // near band: gather
#pragma unroll
      for (int fj = 0; fj < 4; ++fj) {
        const int jl = fj * 16 + lr;
        const bool ok = mask[(size_t)b * SS + j0 + jl] != 0;
        const unsigned short* prow = p2cb + (size_t)(j0 + jl) * TWOK;
        const int dl0 = dbase - fj * 16 - j0;
#pragma unroll
        for (int r = 0; r < 4; ++r) {
          const int dl = dl0 + r;
          const int cc = imin(imax(dl + 512, 0), 1023);
          const int cp = imin(imax(512 - dl, 0), 1023);
          const float s = (sacc[fj][r] + bfu(c2prow[r][cc]) + bfu(prow[cp])) * ATT_SCALE;
          pvv[fj][r] = ok ? s : -1e9f;
        }
      }
    }

    // ---- online softmax
#pragma unroll
    for (int r = 0; r < 4; ++r) {
      float m = fmaxf(fmaxf(pvv[0][r], pvv[1][r]), fmaxf(pvv[2][r], pvv[3][r]));
#pragma unroll
      for (int dd = 1; dd < 16; dd <<= 1) m = fmaxf(m, __shfl_xor(m, dd, 64));
      const float mnew = fmaxf(mprev[r], m);
      const float corr = __expf(mprev[r] - mnew);
      float rs = 0.f;
#pragma unroll
      for (int fj = 0; fj < 4; ++fj) { pvv[fj][r] = __expf(pvv[fj][r] - mnew); rs += pvv[fj][r]; }
#pragma unroll
      for (int dd = 1; dd < 16; dd <<= 1) rs += __shfl_xor(rs, dd, 64);
      lsum[r] = lsum[r] * corr + rs;
      mprev[r] = mnew;
#pragma unroll
      for (int fd = 0; fd < 4; ++fd) oacc[fd][r] *= corr;
    }

    // ---- P -> per-wave LDS band (no barrier: wave-private)
#pragma unroll
    for (int fj = 0; fj < 4; ++fj)
#pragma unroll
      for (int r = 0; r < 4; ++r)
        Ps[wv][lg * 4 + r][fj * 16 + lr] = f2bf(pvv[fj][r]);

    // ---- PV
    const s16x8 pa0 = *(const s16x8*)&Ps[wv][lr][lg * 8];
    const s16x8 pa1 = *(const s16x8*)&Ps[wv][lr][32 + lg * 8];
#pragma unroll
    for (int fd = 0; fd < 4; ++fd) {
      const short* vrow = vT + bhoff + (size_t)(fd * 16 + lr) * SS + j0 + lg * 8;
      const s16x8 v0 = *(const s16x8*)vrow;
      const s16x8 v1 = *(const s16x8*)(vrow + 32);
      oacc[fd] = MFMA16(pa0, v0, oacc[fd]);
      oacc[fd] = MFMA16(pa1, v1, oacc[fd]);
    }
  }

  // ---- split-KV merge across the 4 waves
#pragma unroll
  for (int fd = 0; fd < 4; ++fd)
#pragma unroll
    for (int r = 0; r < 4; ++r)
      Om[wv][lg * 4 + r][fd * 16 + lr] = oacc[fd][r];
  if (lr == 0) {
#pragma unroll
    for (int r = 0; r < 4; ++r) { Mm[wv][lg * 4 + r] = mprev[r]; Lm[wv][lg * 4 + r] = lsum[r]; }
  }
  __syncthreads();

  // each wave finalizes one 16-col slice (cols wv*16 + lr)
#pragma unroll
  for (int r = 0; r < 4; ++r) {
    const int il = lg * 4 + r;
    float mt = fmaxf(fmaxf(Mm[0][il], Mm[1][il]), fmaxf(Mm[2][il], Mm[3][il]));
    float L = 0.f, o = 0.f;
#pragma unroll
    for (int w = 0; w < 4; ++w) {
      const float sc = __expf(Mm[w][il] - mt);
      L += Lm[w][il] * sc;
      o += Om[w][il][wv * 16 + lr] * sc;
    }
    ao[((size_t)b * SS + i0 + il) * HIDN + h * DH + wv * 16 + lr] = f2bf(o / L);
  }
}

// ---------------------------------------------------------------- launch
extern "C" void kernel_launch(void* const* d_in, const int* in_sizes, int n_in,
                              void* d_out, int out_size, void* d_ws, size_t ws_size,
                              hipStream_t stream) {
  const float* x   = (const float*)d_in[0];
  const int* mask  = (const int*)d_in[1];
  const float* Wq  = (const float*)d_in[2];  const float* bq  = (const float*)d_in[3];
  const float* Wk  = (const float*)d_in[4];  const float* bk  = (const float*)d_in[5];
  const float* Wv  = (const float*)d_in[6];  const float* bv  = (const float*)d_in[7];
  const float* Wo  = (const float*)d_in[8];  const float* bo  = (const float*)d_in[9];
  const float* rel = (const float*)d_in[10];
  const float* Wpk = (const float*)d_in[11]; const float* bpk = (const float*)d_in[12];
  const float* Wpq = (const float*)d_in[13]; const float* bpq = (const float*)d_in[14];
  const float* g1  = (const float*)d_in[15]; const float* be1 = (const float*)d_in[16];
  const float* g2  = (const float*)d_in[17]; const float* be2 = (const float*)d_in[18];
  const float* W1  = (const float*)d_in[19]; const float* bf1 = (const float*)d_in[20];
  const float* W2  = (const float*)d_in[21]; const float* bf2 = (const float*)d_in[22];
  float* out = (float*)d_out;

  // ---- liveness-based layout, total ~100 MB (+64KB) < 114 MB proven ----
  char* ws = (char*)d_ws;
  const size_t MB = (size_t)1 << 20;
  // persistent
  short* aoB   = (short*)(ws + 0 * MB);    // 8 MB
  short* qhB   = (short*)(ws + 8 * MB);    // 8 MB
  short* khB   = (short*)(ws + 16 * MB);   // 8 MB
  short* vTB   = (short*)(ws + 24 * MB);   // 8 MB
  short* poskB = (short*)(ws + 32 * MB);   // 2 MB
  short* posqB = (short*)(ws + 34 * MB);   // 2 MB
  // transient region [36 MB, 100 MB)
  short* xn    = (short*)(ws + 36 * MB);   // 8 MB   (stage 1-3)
  short* WqT   = (short*)(ws + 44 * MB);
  short* WkT   = (short*)(ws + 46 * MB);
  short* WvT   = (short*)(ws + 48 * MB);
  short* WpkT  = (short*)(ws + 50 * MB);
  short* WpqT  = (short*)(ws + 52 * MB);
  short* relbf = (short*)(ws + 54 * MB);
  short* c2pG  = (short*)(ws + 36 * MB);   // 32 MB  (stage 4)
  short* p2cG  = (short*)(ws + 68 * MB);   // 32 MB
  short* WoT   = (short*)(ws + 68 * MB);   // stage 5 (c2p/p2c dead)
  short* hnB   = (short*)(ws + 70 * MB);
  short* W1T   = (short*)(ws + 78 * MB);
  short* W2T   = (short*)(ws + 86 * MB);
  short* midB  = (short*)(ws + 36 * MB);   // 32 MB
  short* p2cE  = (short*)(ws + 100 * MB);  // 64 KB edge columns
  (void)ws_size; (void)in_sizes; (void)n_in; (void)out_size;

  const int M = BB * SS;  // 4096

  // ---- stage 1
  k_tcast<<<dim3(32, 32), 256, 0, stream>>>(Wq, WqT, 1024, 1024);
  k_tcast<<<dim3(32, 32), 256, 0, stream>>>(Wk, WkT, 1024, 1024);
  k_tcast<<<dim3(32, 32), 256, 0, stream>>>(Wv, WvT, 1024, 1024);
  k_tcast<<<dim3(32, 32), 256, 0, stream>>>(Wpk, WpkT, 1024, 1024);
  k_tcast<<<dim3(32, 32), 256, 0, stream>>>(Wpq, WpqT, 1024, 1024);
  k_cast<<<1024, 256, 0, stream>>>(rel, relbf, 1024 * 1024 / 4);
  k_ln<<<M, 256, 0, stream>>>(x, g1, be1, xn);

  // ---- stage 2
  k_gemm<OM_HEADS><<<dim3(8, 32), 256, 0, stream>>>(xn, WqT, bq, nullptr, qhB, M, 1024, 1024);
  k_gemm<OM_HEADS><<<dim3(8, 32), 256, 0, stream>>>(xn, WkT, bk, nullptr, khB, M, 1024, 1024);
  k_gemm<OM_VT><<<dim3(8, 32), 256, 0, stream>>>(xn, WvT, bv, nullptr, vTB, M, 1024, 1024);
  k_gemm<OM_POS><<<dim3(8, 8), 256, 0, stream>>>(relbf, WpkT, bpk, nullptr, poskB, 1024, 1024, 1024);
  k_gemm<OM_POS><<<dim3(8, 8), 256, 0, stream>>>(relbf, WpqT, bpq, nullptr, posqB, 1024, 1024, 1024);

  // ---- stage 4: attention in 4 head-groups
  for (int g = 0; g < NHH / HG; ++g) {
    const int h0 = g * HG;
    k_posgemm<<<dim3(8, 16, 16), 256, 0, stream>>>(qhB, khB, poskB, posqB, c2pG, p2cG, p2cE, h0);
    k_attn<<<1024, 256, 0, stream>>>(qhB, khB, vTB, c2pG, p2cG, p2cE, mask, aoB, h0);
  }

  // ---- stage 5
  k_tcast<<<dim3(32, 32), 256, 0, stream>>>(Wo, WoT, 1024, 1024);
  k_gemm<OM_RESID><<<dim3(8, 32), 256, 0, stream>>>(aoB, WoT, bo, x, out, M, 1024, 1024);
  k_ln<<<M, 256, 0, stream>>>(out, g2, be2, hnB);
  k_tcast<<<dim3(128, 32), 256, 0, stream>>>(W1, W1T, 1024, 4096);
  k_tcast<<<dim3(32, 128), 256, 0, stream>>>(W2, W2T, 4096, 1024);
  k_gemm<OM_GELU><<<dim3(32, 32), 256, 0, stream>>>(hnB, W1T, bf1, nullptr, midB, M, 4096, 1024);
  k_gemm<OM_RESID><<<dim3(8, 32), 256, 0, stream>>>(midB, W2T, bf2, out, out, M, 1024, 4096);
}